// Round 3
// baseline (3262.167 us; speedup 1.0000x reference)
//
#include <hip/hip_runtime.h>
#include <hip/hip_bf16.h>
#include <math.h>

// Problem constants
#define BB 256
#define AA 64
#define DIN 512
#define HH_ 1024
#define HHALF 512
#define OUTD 256
#define LL 3
#define ROWS (BB * AA)          // 16384
#define HN ((long)ROWS * HH_)   // 16,777,216 elements per activation buffer

typedef float f32x4 __attribute__((ext_vector_type(4)));
typedef __bf16 bf16x8 __attribute__((ext_vector_type(8)));
typedef __bf16 bf16x4 __attribute__((ext_vector_type(4)));

__device__ __forceinline__ void gld_lds16(const void* g, void* l) {
    __builtin_amdgcn_global_load_lds(
        (const __attribute__((address_space(1))) unsigned int*)g,
        (__attribute__((address_space(3))) unsigned int*)l, 16, 0, 0);
}

// ---------------------------------------------------------------------------
// 256x256 bf16 GEMM, BK=32, 64 KiB LDS -> 2 blocks/CU (R3).
//   C(bf16) = A @ Bt^T + bias
// A: [M][K] bf16 (lda=K), Bt: [N][K] bf16 (ldb=K), bias: f32[N], C: [M][ldc].
// grid = (N/256, M/256), 512 threads. Requires M%256==0, N%256==0, K%32==0,
// K/32 >= 2, grid-size % 8 == 0.
// BK=32 rows (64 B) are naturally uniform over all 8 LDS granule classes ->
// no swizzle needed; staging is fully linear. 2 resident blocks/CU cover
// each other's vmcnt/barrier stalls (R2 showed ~50% stall at 1 block/CU).
// ---------------------------------------------------------------------------
__global__ __launch_bounds__(512, 4) void mfma_gemm256(
    const __bf16* __restrict__ A, const __bf16* __restrict__ Bt,
    const float* __restrict__ bias, __bf16* __restrict__ C,
    int K, int ldc)
{
    // 2 buffers x (A: 256x32 + B: 256x32) bf16 = 64 KiB
    __shared__ __bf16 sA[2][256 * 32];
    __shared__ __bf16 sB[2][256 * 32];

    const int NT = K >> 5;            // K-tiles of 32
    const int t = threadIdx.x;
    const int wv = t >> 6;            // 0..7
    const int lane = t & 63;
    const int quad = lane >> 4;       // 0..3
    const int lrow = lane & 15;
    const int wr = wv >> 2;           // wave m-tile (0..1) -> 128 rows
    const int wc = wv & 3;            // wave n-tile (0..3) -> 64 cols
    const int koff = quad * 8;        // 16B granule within 32-elem row

    // ---- XCD-aware bijective block swizzle (nwg % 8 == 0) ----
    const int nbx = gridDim.x;
    const int nwg = nbx * gridDim.y;
    const int flat = blockIdx.y * nbx + blockIdx.x;
    const int s_ = (flat & 7) * (nwg >> 3) + (flat >> 3);
    const int bx = s_ % nbx, by = s_ / nbx;
    const int m0 = by * 256, n0 = bx * 256;

    f32x4 acc[8][4] = {};
    bf16x8 af[4], bLo[2], bHi[2];

    // Stage one 128-row half-tile (8 KiB) of K-tile tt: exactly 1 load/thread.
    // Linear LDS dest == linear global source (no swizzle at BK=32).
    auto STAGE = [&](int tt, int isB, int half) {
        __bf16* region = (isB ? sB[tt & 1] : sA[tt & 1]) + half * 4096;
        const __bf16* g = isB ? Bt : A;
        const long row0 = (long)(isB ? n0 : m0) + half * 128;
        const int k0 = tt << 5;
        gld_lds16(g + (row0 + (t >> 2)) * (long)K + k0 + (t & 3) * 8,
                  region + wv * 512);
    };
    auto READ_A = [&](const __bf16* buf, int rb) {
#pragma unroll
        for (int fr = 0; fr < 4; ++fr)
            af[fr] = *(const bf16x8*)(buf + (rb + fr * 16 + lrow) * 32 + koff);
    };
    auto READ_B = [&](bf16x8 (&bf)[2], const __bf16* buf, int rb) {
#pragma unroll
        for (int nf = 0; nf < 2; ++nf)
            bf[nf] = *(const bf16x8*)(buf + (rb + nf * 16 + lrow) * 32 + koff);
    };
    auto MF = [&](bf16x8 (&bf)[2], int mh, int nh) {
        __builtin_amdgcn_s_setprio(1);
#pragma unroll
        for (int fr = 0; fr < 4; ++fr)
#pragma unroll
            for (int nf = 0; nf < 2; ++nf)
                acc[mh * 4 + fr][nh * 2 + nf] =
                    __builtin_amdgcn_mfma_f32_16x16x32_bf16(
                        af[fr], bf[nf], acc[mh * 4 + fr][nh * 2 + nf],
                        0, 0, 0);
        __builtin_amdgcn_s_setprio(0);
    };

    // ---- prologue: tile0 fully staged (4 loads); tile1 B0,A0 in flight ----
    STAGE(0, 0, 0); STAGE(0, 1, 0); STAGE(0, 0, 1); STAGE(0, 1, 1);
    STAGE(1, 1, 0); STAGE(1, 0, 0);
    asm volatile("s_waitcnt vmcnt(2)" ::: "memory");   // tile0 resident
    __builtin_amdgcn_s_barrier();

    for (int j = 0; j < NT; ++j) {
        const __bf16* cA = sA[j & 1];
        const __bf16* cB = sB[j & 1];
        // ---- segment 1: C00 + C01; stage (j+1, B1), (j+1, A1) ----
        READ_A(cA, wr * 128);
        READ_B(bLo, cB, wc * 64);
        if (j + 1 < NT) STAGE(j + 1, 1, 1);
        MF(bLo, 0, 0);
        READ_B(bHi, cB, wc * 64 + 32);
        if (j + 1 < NT) STAGE(j + 1, 0, 1);
        MF(bHi, 0, 1);
        // barrier: all B reads of buf[j&1] complete before B0(j+2) overwrite
        __builtin_amdgcn_s_barrier();
        // ---- segment 2: C10; stage (j+2, B0) ----
        READ_A(cA, wr * 128 + 64);
        if (j + 2 < NT) STAGE(j + 2, 1, 0);
        MF(bLo, 1, 0);
        // barrier: A reads of buf[j&1] complete before A0(j+2) overwrite
        __builtin_amdgcn_s_barrier();
        // ---- segment 3: C11; stage (j+2, A0); counted-vmcnt boundary ----
        if (j + 2 < NT) STAGE(j + 2, 0, 0);
        MF(bHi, 1, 1);
        if (j < NT - 2)       asm volatile("s_waitcnt vmcnt(2)" ::: "memory");
        else if (j == NT - 2) asm volatile("s_waitcnt vmcnt(0)" ::: "memory");
        __builtin_amdgcn_s_barrier();   // tile j+1 resident for all waves
    }

    // ---- epilogue: bias + bf16 store ----
#pragma unroll
    for (int mi = 0; mi < 8; ++mi) {
#pragma unroll
        for (int p = 0; p < 4; ++p) {
            const int m = m0 + wr * 128 + mi * 16 + quad * 4 + p;
#pragma unroll
            for (int ni = 0; ni < 4; ++ni) {
                const int n = n0 + wc * 64 + ni * 16 + lrow;
                C[(long)m * ldc + n] = (__bf16)(acc[mi][ni][p] + bias[n]);
            }
        }
    }
}

// ---------------------------------------------------------------------------
// bf16 MFMA GEMM (m97 structure): C = act(A @ Bt^T + bias)  [kept for heads]
// ---------------------------------------------------------------------------
#define TK 32
template <int ACT, int OUT_BF16, int SWZ>  // ACT: 1 = exact GELU
__global__ __launch_bounds__(256) void mfma_gemm(
    const __bf16* __restrict__ Abase, const __bf16* __restrict__ Btbase,
    const float* __restrict__ biasBase, float* __restrict__ Cf,
    __bf16* __restrict__ Cb,
    int M, int N, int K, int lda, int ldb, int ldc,
    long sA, long sB, long sBias, long sC)
{
    const int z = blockIdx.z;
    const __bf16* A  = Abase  + (long)z * sA;
    const __bf16* Bt = Btbase + (long)z * sB;
    const float* bias = biasBase + (long)z * sBias;

    int bx = blockIdx.x, by = blockIdx.y;
    if (SWZ) {  // grid must be 24 x 128
        int lid = by * 24 + bx;
        int xcd = lid & 7, s = lid >> 3;       // s: 0..383
        by = (xcd >> 1) * 32 + s / 12;
        bx = (xcd & 1) * 12 + s % 12;
    }
    const int m0 = by * 128;
    const int n0 = bx * 128;

    __shared__ __bf16 sAt[128 * TK];   // [m][k]
    __shared__ __bf16 sBt[128 * TK];   // [n][k]

    const int t    = threadIdx.x;
    const int wv   = t >> 6;
    const int lane = t & 63;
    const int quad = lane >> 4;
    const int lrow = lane & 15;
    const int wm = (wv >> 1) * 64;
    const int wn = (wv & 1) * 64;

    f32x4 acc[4][4] = {};

    const int sr = t >> 2;
    const int sk = (t & 3) * 8;
    __bf16* la0 = sAt + wv * 512;
    __bf16* la1 = sAt + 64 * TK + wv * 512;
    __bf16* lb0 = sBt + wv * 512;
    __bf16* lb1 = sBt + 64 * TK + wv * 512;

    for (int k0 = 0; k0 < K; k0 += TK) {
        gld_lds16(A  + (long)(m0 + sr)      * lda + k0 + sk, la0);
        gld_lds16(A  + (long)(m0 + 64 + sr) * lda + k0 + sk, la1);
        gld_lds16(Bt + (long)(n0 + sr)      * ldb + k0 + sk, lb0);
        gld_lds16(Bt + (long)(n0 + 64 + sr) * ldb + k0 + sk, lb1);
        __syncthreads();

        bf16x8 af[4], bfr[4];
#pragma unroll
        for (int i = 0; i < 4; ++i)
            af[i] = *(const bf16x8*)(sAt + (wm + i * 16 + lrow) * TK + quad * 8);
#pragma unroll
        for (int j = 0; j < 4; ++j)
            bfr[j] = *(const bf16x8*)(sBt + (wn + j * 16 + lrow) * TK + quad * 8);
#pragma unroll
        for (int i = 0; i < 4; ++i)
#pragma unroll
            for (int j = 0; j < 4; ++j)
                acc[i][j] = __builtin_amdgcn_mfma_f32_16x16x32_bf16(
                    af[i], bfr[j], acc[i][j], 0, 0, 0);
        __syncthreads();
    }

#pragma unroll
    for (int i = 0; i < 4; ++i) {
#pragma unroll
        for (int p = 0; p < 4; ++p) {
            const int m = m0 + wm + i * 16 + quad * 4 + p;
#pragma unroll
            for (int j = 0; j < 4; ++j) {
                const int n = n0 + wn + j * 16 + lrow;
                float val = acc[i][j][p] + bias[n];
                if (ACT == 1) val = 0.5f * val * (1.0f + erff(val * 0.70710678118654752f));
                if (OUT_BF16) Cb[(long)z * sC + (long)m * ldc + n] = (__bf16)val;
                else          Cf[(long)z * sC + (long)m * ldc + n] = val;
            }
        }
    }
}

// ---------------------------------------------------------------------------
// fp32 -> bf16 flat cast
// ---------------------------------------------------------------------------
__global__ __launch_bounds__(256) void cast_kernel(
    const float* __restrict__ in, __bf16* __restrict__ out)
{
    long i = ((long)blockIdx.x * 256 + threadIdx.x) * 4;
    float4 v = *(const float4*)(in + i);
    bf16x4 o = {(__bf16)v.x, (__bf16)v.y, (__bf16)v.z, (__bf16)v.w};
    *(bf16x4*)(out + i) = o;
}

// ---------------------------------------------------------------------------
// Generic transpose + cast: fp32 [R][C] -> bf16 [C][R], batched over z.
// ---------------------------------------------------------------------------
__global__ __launch_bounds__(256) void transpose_cast_kernel(
    const float* __restrict__ in, __bf16* __restrict__ out,
    int R, int C, long sIn, long sOut)
{
    const float* src = in + (long)blockIdx.z * sIn;
    __bf16* dst = out + (long)blockIdx.z * sOut;
    __shared__ float tile[32][33];
    const int r0 = blockIdx.y * 32, c0 = blockIdx.x * 32;
    const int tx = threadIdx.x & 31, ty = threadIdx.x >> 5;
#pragma unroll
    for (int i = 0; i < 32; i += 8)
        tile[ty + i][tx] = src[(long)(r0 + ty + i) * C + c0 + tx];
    __syncthreads();
#pragma unroll
    for (int i = 0; i < 32; i += 8)
        dst[(long)(c0 + ty + i) * R + r0 + tx] = (__bf16)tile[tx][ty + i];
}

// ---------------------------------------------------------------------------
// Merged Wq/Wk/Wv transpose: z in [0,9) -> layer z/3, tensor z%3.
// ---------------------------------------------------------------------------
__global__ __launch_bounds__(256) void transpose_qkv_kernel(
    const float* __restrict__ Wq, const float* __restrict__ Wk,
    const float* __restrict__ Wv, __bf16* __restrict__ out)
{
    const int zz = blockIdx.z;
    const int layer = zz / 3, which = zz - layer * 3;
    const float* src = (which == 0 ? Wq : which == 1 ? Wk : Wv) + (long)layer * 1048576;
    __bf16* dst = out + (long)layer * 3145728 + (long)which * 1048576;
    __shared__ float tile[32][33];
    const int r0 = blockIdx.y * 32, c0 = blockIdx.x * 32;
    const int tx = threadIdx.x & 31, ty = threadIdx.x >> 5;
#pragma unroll
    for (int i = 0; i < 32; i += 8)
        tile[ty + i][tx] = src[(long)(r0 + ty + i) * 1024 + c0 + tx];
    __syncthreads();
#pragma unroll
    for (int i = 0; i < 32; i += 8)
        dst[(long)(c0 + ty + i) * 1024 + r0 + tx] = (__bf16)tile[tx][ty + i];
}

// ---------------------------------------------------------------------------
// Concatenate bq|bk|bv per layer into [L][3072]
// ---------------------------------------------------------------------------
__global__ __launch_bounds__(256) void qkv_bias_kernel(
    const float* __restrict__ bq, const float* __restrict__ bk,
    const float* __restrict__ bv, float* __restrict__ ob)
{
    int i = blockIdx.x * 256 + threadIdx.x;
    if (i >= LL * 3072) return;
    int l = i / 3072, j = i - l * 3072;
    float v = (j < 1024) ? bq[l * 1024 + j]
            : (j < 2048) ? bk[l * 1024 + j - 1024]
                         : bv[l * 1024 + j - 2048];
    ob[i] = v;
}

// ---------------------------------------------------------------------------
// Wave-per-row LayerNorm over H=1024: 4 rows per block, shuffle reductions.
// ---------------------------------------------------------------------------
__global__ __launch_bounds__(256) void ln_kernel(
    const __bf16* __restrict__ x, const float* __restrict__ g,
    const float* __restrict__ b, __bf16* __restrict__ outb)
{
    const int wv = threadIdx.x >> 6, lane = threadIdx.x & 63;
    const long row = blockIdx.x * 4 + wv;
    const __bf16* xr = x + row * HH_;
    float v[16];
    float s = 0.f, s2 = 0.f;
#pragma unroll
    for (int i = 0; i < 4; ++i) {
        bf16x4 vb = *(const bf16x4*)(xr + i * 256 + lane * 4);
#pragma unroll
        for (int j = 0; j < 4; ++j) {
            float f = (float)vb[j];
            v[i * 4 + j] = f; s += f; s2 += f * f;
        }
    }
#pragma unroll
    for (int m = 1; m < 64; m <<= 1) { s += __shfl_xor(s, m); s2 += __shfl_xor(s2, m); }
    float mu = s * (1.0f / 1024.0f);
    float var = s2 * (1.0f / 1024.0f) - mu * mu;
    float rstd = rsqrtf(var + 1e-5f);
    __bf16* orow = outb + row * HH_;
#pragma unroll
    for (int i = 0; i < 4; ++i) {
        float4 gv = *(const float4*)(g + i * 256 + lane * 4);
        float4 bv = *(const float4*)(b + i * 256 + lane * 4);
        bf16x4 ob = {(__bf16)((v[i*4+0] - mu) * rstd * gv.x + bv.x),
                     (__bf16)((v[i*4+1] - mu) * rstd * gv.y + bv.y),
                     (__bf16)((v[i*4+2] - mu) * rstd * gv.z + bv.z),
                     (__bf16)((v[i*4+3] - mu) * rstd * gv.w + bv.w)};
        *(bf16x4*)(orow + i * 256 + lane * 4) = ob;
    }
}

// ---------------------------------------------------------------------------
// Fused attention per batch z: scores (MFMA) -> sinkhorn (LDS, no-max) -> P@V.
// ---------------------------------------------------------------------------
__global__ __launch_bounds__(256) void attn_kernel(
    const __bf16* __restrict__ qkv, __bf16* __restrict__ att)
{
    const int z = blockIdx.x;
    __shared__ __bf16 sQ[64 * 32];
    __shared__ __bf16 sK[64 * 32];
    __shared__ float la[64 * 65];
    __shared__ float ps[4][64];
    __shared__ __bf16 sP[64 * 68];    // exp(P) bf16, padded
    __shared__ __bf16 sVT[64 * 68];   // V^T tile [n][c], padded

    const int t = threadIdx.x;
    const int wv = t >> 6, lane = t & 63;
    const int quad = lane >> 4, lrow = lane & 15;
    const int wm = (wv >> 1) * 32, wn = (wv & 1) * 32;

    // ---- phase 1: scores = Q K^T / 32 -> la ----
    {
        const int srow = t >> 2;
        const int skoff = (t & 3) * 8;
        __bf16* lq = sQ + wv * 512;
        __bf16* lk = sK + wv * 512;
        const __bf16* Q = qkv + (long)z * 64 * 3072;
        const __bf16* K = Q + 1024;

        f32x4 acc[2][2] = {};
        for (int k0 = 0; k0 < 1024; k0 += 32) {
            gld_lds16(Q + (long)srow * 3072 + k0 + skoff, lq);
            gld_lds16(K + (long)srow * 3072 + k0 + skoff, lk);
            __syncthreads();
            bf16x8 af[2], bfr[2];
#pragma unroll
            for (int i = 0; i < 2; ++i)
                af[i] = *(const bf16x8*)(sQ + (wm + i * 16 + lrow) * 32 + quad * 8);
#pragma unroll
            for (int j = 0; j < 2; ++j)
                bfr[j] = *(const bf16x8*)(sK + (wn + j * 16 + lrow) * 32 + quad * 8);
#pragma unroll
            for (int i = 0; i < 2; ++i)
#pragma unroll
                for (int j = 0; j < 2; ++j)
                    acc[i][j] = __builtin_amdgcn_mfma_f32_16x16x32_bf16(
                        af[i], bfr[j], acc[i][j], 0, 0, 0);
            __syncthreads();
        }
#pragma unroll
        for (int i = 0; i < 2; ++i)
#pragma unroll
            for (int p = 0; p < 4; ++p) {
                const int r = wm + i * 16 + quad * 4 + p;
#pragma unroll
                for (int j = 0; j < 2; ++j)
                    la[r * 65 + wn + j * 16 + lrow] = acc[i][j][p] * 0.03125f;
            }
        __syncthreads();
    }

    // ---- phase 2: sinkhorn, 50 iters, no max subtraction ----
    for (int it = 0; it < 50; ++it) {
        {   // row phase: row = lane, cols wv*16..+15
            float vr[16];
            float sum = 0.f;
#pragma unroll
            for (int i = 0; i < 16; ++i) vr[i] = la[lane * 65 + wv * 16 + i];
#pragma unroll
            for (int i = 0; i < 16; ++i) sum += __expf(vr[i]);
            ps[wv][lane] = sum;
            __syncthreads();
            float lse = __logf(ps[0][lane] + ps[1][lane] + ps[2][lane] + ps[3][lane]);
#pragma unroll
            for (int i = 0; i < 16; ++i) la[lane * 65 + wv * 16 + i] = vr[i] - lse;
            __syncthreads();
        }
        {   // col phase: col = lane, rows wv*16..+15
            float vr[16];
            float sum = 0.f;
#pragma unroll
            for (int i = 0; i < 16; ++i) vr[i] = la[(wv * 16 + i) * 65 + lane];
#pragma unroll
            for (int i = 0; i < 16; ++i) sum += __expf(vr[i]);
            ps[wv][lane] = sum;
            __syncthreads();
            float lse = __logf(ps[0][lane] + ps[1][lane] + ps[2][lane] + ps[3][lane]);
#pragma unroll
            for (int i = 0; i < 16; ++i) la[(wv * 16 + i) * 65 + lane] = vr[i] - lse;
            __syncthreads();
        }
    }

    // ---- phase 3: P = exp(la) -> bf16 sP ----
#pragma unroll
    for (int i = 0; i < 16; ++i) {
        int idx = t + i * 256;
        int r = idx >> 6, c = idx & 63;
        sP[r * 68 + c] = (__bf16)__expf(la[r * 65 + c]);
    }
    __syncthreads();

    // ---- phase 4: att = P @ V via MFMA, 16 column tiles of 64 ----
    const __bf16* V = qkv + (long)z * 64 * 3072 + 2048;
    const int vc = t >> 2;            // V row (agent c), 0..63
    const int vn = (t & 3) * 16;      // n offset within tile
    for (int tile = 0; tile < 16; ++tile) {
        bf16x8 v0 = *(const bf16x8*)(V + (long)vc * 3072 + tile * 64 + vn);
        bf16x8 v1 = *(const bf16x8*)(V + (long)vc * 3072 + tile * 64 + vn + 8);
#pragma unroll
        for (int j = 0; j < 8; ++j) sVT[(vn + j) * 68 + vc] = v0[j];
#pragma unroll
        for (int j = 0; j < 8; ++j) sVT[(vn + 8 + j) * 68 + vc] = v1[j];
        __syncthreads();

        f32x4 pacc[2][2] = {};
#pragma unroll
        for (int kb = 0; kb < 2; ++kb) {
            bf16x8 af[2], bfr[2];
#pragma unroll
            for (int i = 0; i < 2; ++i) {
                const __bf16* p = sP + (wm + i * 16 + lrow) * 68 + kb * 32 + quad * 8;
                bf16x4 lo = *(const bf16x4*)p;
                bf16x4 hi = *(const bf16x4*)(p + 4);
                af[i] = bf16x8{lo[0], lo[1], lo[2], lo[3], hi[0], hi[1], hi[2], hi[3]};
            }
#pragma unroll
            for (int j = 0; j < 2; ++j) {
                const __bf16* p = sVT + (wn + j * 16 + lrow) * 68 + kb * 32 + quad * 8;
                bf16x4 lo = *(const bf16x4*)p;
                bf16x4 hi = *(const bf16x4*)(p + 4);
                bfr[j] = bf16x8{lo[0], lo[1], lo[2], lo[3], hi[0], hi[1], hi[2], hi[3]};
            }
#pragma unroll
            for (int i = 0; i < 2; ++i)
#pragma unroll
                for (int j = 0; j < 2; ++j)
                    pacc[i][j] = __builtin_amdgcn_mfma_f32_16x16x32_bf16(
                        af[i], bfr[j], pacc[i][j], 0, 0, 0);
        }
#pragma unroll
        for (int i = 0; i < 2; ++i)
#pragma unroll
            for (int p = 0; p < 4; ++p) {
                const int r = wm + i * 16 + quad * 4 + p;
#pragma unroll
                for (int j = 0; j < 2; ++j) {
                    const int n = tile * 64 + wn + j * 16 + lrow;
                    att[((long)z * 64 + r) * HH_ + n] = (__bf16)pacc[i][j][p];
                }
            }
        __syncthreads();
    }
}

// ---------------------------------------------------------------------------
// Wave-per-row mix: 4 rows per block, shuffle reductions, no barriers.
// ---------------------------------------------------------------------------
__global__ __launch_bounds__(256) void mix_kernel(
    const __bf16* __restrict__ nsb_in, const __bf16* __restrict__ att,
    const float* __restrict__ ab, const float* __restrict__ sf,
    __bf16* __restrict__ h,
    const float* __restrict__ ig, const float* __restrict__ ib,
    const float* __restrict__ g2, const float* __restrict__ b2p, int doLN,
    __bf16* __restrict__ nsb_out)
{
    const int wv = threadIdx.x >> 6, lane = threadIdx.x & 63;
    const long row = blockIdx.x * 4 + wv;
    const int a = (int)(row & 63);
    const float sfa = sf[a];

    const __bf16* nr = nsb_in + row * HH_;
    const __bf16* ar = att + row * HH_;
    const float* abr = ab + (long)a * HH_;

    float sc[16];
    float nrm2 = 0.f;
#pragma unroll
    for (int i = 0; i < 4; ++i) {
        bf16x4 nv = *(const bf16x4*)(nr + i * 256 + lane * 4);
        bf16x4 av = *(const bf16x4*)(ar + i * 256 + lane * 4);
        float4 a4 = *(const float4*)(abr + i * 256 + lane * 4);
        float v0 = (0.1f * (float)nv[0] + 0.9f * (float)av[0] + a4.x) * sfa;
        float v1 = (0.1f * (float)nv[1] + 0.9f * (float)av[1] + a4.y) * sfa;
        float v2 = (0.1f * (float)nv[2] + 0.9f * (float)av[2] + a4.z) * sfa;
        float v3 = (0.1f * (float)nv[3] + 0.9f * (float)av[3] + a4.w) * sfa;
        sc[i*4+0] = v0; sc[i*4+1] = v1; sc[i*4+2] = v2; sc[i*4+3] = v3;
        nrm2 += v0 * v0 + v1 * v1 + v2 * v2 + v3 * v3;
    }
#pragma unroll
    for (int m = 1; m < 64; m <<= 1) nrm2 += __shfl_xor(nrm2, m);
    float norm = sqrtf(nrm2);
    float inv = norm > 1.0f ? 1.0f / norm : 1.0f;

    __bf16* hr = h + row * HH_;
    float hn[16];
    float s = 0.f, s2 = 0.f;
#pragma unroll
    for (int i = 0; i < 4; ++i) {
        bf16x4 hv = *(const bf16x4*)(hr + i * 256 + lane * 4);
#pragma unroll
        for (int j = 0; j < 4; ++j) {
            float f = (float)hv[j] + sc[i * 4 + j] * inv;
            hn[i * 4 + j] = f; s += f; s2 += f * f;
        }
    }
    if (!doLN) {
#pragma unroll
        for (int i = 0; i < 4; ++i) {
            bf16x4 ob = {(__bf16)hn[i*4+0], (__bf16)hn[i*4+1],
                         (__bf16)hn[i*4+2], (__bf16)hn[i*4+3]};
            *(bf16x4*)(hr + i * 256 + lane * 4) = ob;
        }
        return;
    }
#pragma unroll
    for (int m = 1; m < 64; m <<= 1) { s += __shfl_xor(s, m); s2 += __shfl_xor(s2, m); }
    float mu = s * (1.0f / 1024.0f);
    float var = s2 * (1.0f / 1024.0f) - mu * mu;
    float rstd = rsqrtf(var + 1e-5f);
    float s_1 = 0.f, s2_1 = 0.f;
#pragma unroll
    for (int i = 0; i < 4; ++i) {
        float4 gv = *(const float4*)(ig + i * 256 + lane * 4);
        float4 bv = *(const float4*)(ib + i * 256 + lane * 4);
        float f0 = (hn[i*4+0] - mu) * rstd * gv.x + bv.x;
        float f1 = (hn[i*4+1] - mu) * rstd * gv.y + bv.y;
        float f2 = (hn[i*4+2] - mu) * rstd * gv.z + bv.z;
        float f3 = (hn[i*4+3] - mu) * rstd * gv.w + bv.w;
        hn[i*4+0] = f0; hn[i*4+1] = f1; hn[i*4+2] = f2; hn[i*4+3] = f3;
        s_1 += f0 + f1 + f2 + f3;
        s2_1 += f0 * f0 + f1 * f1 + f2 * f2 + f3 * f3;
        bf16x4 ob = {(__bf16)f0, (__bf16)f1, (__bf16)f2, (__bf16)f3};
        *(bf16x4*)(hr + i * 256 + lane * 4) = ob;
    }
#pragma unroll
    for (int m = 1; m < 64; m <<= 1) { s_1 += __shfl_xor(s_1, m); s2_1 += __shfl_xor(s2_1, m); }
    mu = s_1 * (1.0f / 1024.0f);
    var = s2_1 * (1.0f / 1024.0f) - mu * mu;
    rstd = rsqrtf(var + 1e-5f);
    __bf16* nor = nsb_out + row * HH_;
#pragma unroll
    for (int i = 0; i < 4; ++i) {
        float4 gv = *(const float4*)(g2 + i * 256 + lane * 4);
        float4 bv = *(const float4*)(b2p + i * 256 + lane * 4);
        bf16x4 ob = {(__bf16)((hn[i*4+0] - mu) * rstd * gv.x + bv.x),
                     (__bf16)((hn[i*4+1] - mu) * rstd * gv.y + bv.y),
                     (__bf16)((hn[i*4+2] - mu) * rstd * gv.z + bv.z),
                     (__bf16)((hn[i*4+3] - mu) * rstd * gv.w + bv.w)};
        *(bf16x4*)(nor + i * 256 + lane * 4) = ob;
    }
}

// ---------------------------------------------------------------------------
extern "C" void kernel_launch(void* const* d_in, const int* in_sizes, int n_in,
                              void* d_out, int out_size, void* d_ws, size_t ws_size,
                              hipStream_t stream)
{
    const float* agent_states = (const float*)d_in[0];
    const float* Win   = (const float*)d_in[1];
    const float* bin_  = (const float*)d_in[2];
    const float* ln_g  = (const float*)d_in[3];
    const float* ln_b  = (const float*)d_in[4];
    const float* Wq    = (const float*)d_in[5];
    const float* bq    = (const float*)d_in[6];
    const float* Wk    = (const float*)d_in[7];
    const float* bk    = (const float*)d_in[8];
    const float* Wv    = (const float*)d_in[9];
    const float* bv    = (const float*)d_in[10];
    const float* ab    = (const float*)d_in[11];
    const float* sf    = (const float*)d_in[12];
    const float* ilg   = (const float*)d_in[13];
    const float* ilb   = (const float*)d_in[14];
    const float* W1    = (const float*)d_in[15];
    const float* b1    = (const float*)d_in[16];
    const float* W2    = (const float*)d_in[17];
    const float* b2    = (const float*)d_in[18];
    float* out = (float*)d_out;

    // ---- workspace layout ----
    float* qbias = (float*)d_ws;                 // 16384 floats (9216 used)
    __bf16* base = (__bf16*)(qbias + 16384);
    __bf16* nsb   = base;                        // HN
    __bf16* h     = nsb + HN;                    // HN
    __bf16* att   = h + HN;                      // HN
    __bf16* qkvb  = att + HN;                    // 3*HN = 50,331,648
    __bf16* Wqkvt = qkvb + 3 * HN;               // 9,437,184
    // pre-loop overlays (att unused until layer 0 attention):
    __bf16* asb  = att;                          // 8,388,608
    __bf16* Wint = att + 8388608;                // 524,288
    // post-loop overlays (qkvb dead after last attention):
    __bf16* W1t = qkvb;                          // 33,554,432
    __bf16* W2t = qkvb + 33554432;               // 8,388,608
    __bf16* yb  = qkvb + 41943040;               // 8,388,608

    // ---- prep: casts / packs ----
    cast_kernel<<<8192, 256, 0, stream>>>(agent_states, asb);
    transpose_cast_kernel<<<dim3(32, 16, 1), 256, 0, stream>>>(Win, Wint, 512, 1024, 0, 0);
    transpose_qkv_kernel<<<dim3(32, 32, 9), 256, 0, stream>>>(Wq, Wk, Wv, Wqkvt);
    qkv_bias_kernel<<<36, 256, 0, stream>>>(bq, bk, bv, qbias);

    // ---- input projection: h(bf16) = asb @ Win^T + bin  (256x256, BK=32) ----
    mfma_gemm256<<<dim3(4, 64), 512, 0, stream>>>(asb, Wint, bin_, h, DIN, HH_);
    ln_kernel<<<ROWS / 4, 256, 0, stream>>>(h, ln_g, ln_b, nsb);

    for (int i = 0; i < LL; ++i) {
        // QKV: [16384 x 3072] = nsb @ [Wq^T|Wk^T|Wv^T]  (256x256, BK=32)
        mfma_gemm256<<<dim3(12, 64), 512, 0, stream>>>(
            nsb, Wqkvt + (long)i * 3145728, qbias + i * 3072, qkvb, HH_, 3072);
        attn_kernel<<<BB, 256, 0, stream>>>(qkvb, att);
        const int last = (i == LL - 1);
        mix_kernel<<<ROWS / 4, 256, 0, stream>>>(
            nsb, att, ab + (long)i * AA * HH_, sf + i * AA, h,
            ilg + (last ? 0 : i) * HH_, ilb + (last ? 0 : i) * HH_,
            ln_g + (last ? 0 : (i + 1)) * HH_, ln_b + (last ? 0 : (i + 1)) * HH_,
            last ? 0 : 1, nsb);
    }

    // ---- heads ----
    transpose_cast_kernel<<<dim3(16, 32, 64), 256, 0, stream>>>(W1, W1t, 1024, 512,
                                                                524288, 524288);
    transpose_cast_kernel<<<dim3(8, 16, 64), 256, 0, stream>>>(W2, W2t, 512, 256,
                                                               131072, 131072);
    mfma_gemm<1, 1, 0><<<dim3(4, 2, 64), 256, 0, stream>>>(
        h, W1t, b1, nullptr, yb, BB, HHALF, HH_,
        AA * HH_, HH_, AA * HHALF, HH_, (long)HHALF * HH_, HHALF, HHALF);
    mfma_gemm<0, 0, 0><<<dim3(2, 2, 64), 256, 0, stream>>>(
        yb, W2t, b2, out, nullptr, BB, OUTD, HHALF,
        AA * HHALF, HHALF, AA * OUTD, HHALF, (long)OUTD * HHALF, OUTD, OUTD);
}

// Round 5
// 1017.314 us; speedup vs baseline: 3.2066x; 3.2066x over previous
//
#include <hip/hip_runtime.h>
#include <hip/hip_bf16.h>
#include <math.h>

// Problem constants
#define BB 256
#define AA 64
#define DIN 512
#define HH_ 1024
#define HHALF 512
#define OUTD 256
#define LL 3
#define ROWS (BB * AA)          // 16384
#define HN ((long)ROWS * HH_)   // 16,777,216 elements per activation buffer

typedef float f32x4 __attribute__((ext_vector_type(4)));
typedef __bf16 bf16x8 __attribute__((ext_vector_type(8)));
typedef __bf16 bf16x4 __attribute__((ext_vector_type(4)));

__device__ __forceinline__ void gld_lds16(const void* g, void* l) {
    __builtin_amdgcn_global_load_lds(
        (const __attribute__((address_space(1))) unsigned int*)g,
        (__attribute__((address_space(3))) unsigned int*)l, 16, 0, 0);
}

// ---------------------------------------------------------------------------
// 256x256 8-phase bf16 GEMM (R2-verified version, passed at 115.3 us):
//   C(bf16) = A @ Bt^T + bias
// A: [M][K] bf16 (lda=K), Bt: [N][K] bf16 (ldb=K), bias: f32[N], C: [M][ldc].
// grid = (N/256, M/256), 512 threads. Requires M%256==0, N%256==0, K%64==0,
// K/64 >= 2, grid-size % 8 == 0.
// 3 barriers per K-tile (only the write-after-read-mandated ones) and
// s-outer MFMA order (no dependent back-to-back MFMA pairs).
// ---------------------------------------------------------------------------
__global__ __launch_bounds__(512) void mfma_gemm256(
    const __bf16* __restrict__ A, const __bf16* __restrict__ Bt,
    const float* __restrict__ bias, __bf16* __restrict__ C,
    int K, int ldc)
{
    // 2 buffers x (A: 256x64 + B: 256x64) bf16 = 128 KiB
    __shared__ __bf16 sA[2][256 * 64];
    __shared__ __bf16 sB[2][256 * 64];

    const int NT = K >> 6;            // K-tiles of 64
    const int t = threadIdx.x;
    const int wv = t >> 6;            // 0..7
    const int lane = t & 63;
    const int quad = lane >> 4;       // 0..3
    const int lrow = lane & 15;
    const int wr = wv >> 2;           // wave m-tile (0..1) -> 128 rows
    const int wc = wv & 3;            // wave n-tile (0..3) -> 64 cols
    // swizzle: logical byte-in-row ^ ((row&7)<<4); row&7 == lane&7 for all frags
    const int swz = (lane & 7) << 3;            // element units
    const int cs0 = (quad * 8) ^ swz;           // k-sub 0
    const int cs1 = (32 + quad * 8) ^ swz;      // k-sub 1

    // ---- XCD-aware bijective block swizzle (nwg % 8 == 0) ----
    const int nbx = gridDim.x;
    const int nwg = nbx * gridDim.y;
    const int flat = blockIdx.y * nbx + blockIdx.x;
    const int s_ = (flat & 7) * (nwg >> 3) + (flat >> 3);
    const int bx = s_ % nbx, by = s_ / nbx;
    const int m0 = by * 256, n0 = bx * 256;

    f32x4 acc[8][4] = {};
    bf16x8 af[4][2], bLo[2][2], bHi[2][2];

    // Stage one 128-row half-tile (16 KiB) of K-tile tt.
    // Linear LDS dest (global_load_lds requirement) + inverse-swizzled global
    // source so that swizzled ds_read addresses see logical data.
    auto STAGE = [&](int tt, int isB, int half) {
        __bf16* region = (isB ? sB[tt & 1] : sA[tt & 1]) + half * 8192;
        const __bf16* g = isB ? Bt : A;
        const long row0 = (long)(isB ? n0 : m0) + half * 128;
        const int k0 = tt << 6;
#pragma unroll
        for (int it = 0; it < 2; ++it) {
            const int r = it * 64 + (t >> 3);                  // local row 0..127
            const int kc = (((t & 7) ^ (r & 7)) << 3);         // inv-swizzled col
            gld_lds16(g + (row0 + r) * (long)K + k0 + kc,
                      region + it * 4096 + wv * 512);
        }
    };
    auto READ_A = [&](const __bf16* buf, int rb) {
#pragma unroll
        for (int fr = 0; fr < 4; ++fr) {
            const __bf16* p = buf + (rb + fr * 16 + lrow) * 64;
            af[fr][0] = *(const bf16x8*)(p + cs0);
            af[fr][1] = *(const bf16x8*)(p + cs1);
        }
    };
    auto READ_B = [&](bf16x8 (&bf)[2][2], const __bf16* buf, int rb) {
#pragma unroll
        for (int nf = 0; nf < 2; ++nf) {
            const __bf16* p = buf + (rb + nf * 16 + lrow) * 64;
            bf[nf][0] = *(const bf16x8*)(p + cs0);
            bf[nf][1] = *(const bf16x8*)(p + cs1);
        }
    };
    // s-outer: consecutive MFMAs independent; dependent partner 8 issues later
    auto MF = [&](bf16x8 (&bf)[2][2], int mh, int nh) {
        __builtin_amdgcn_s_setprio(1);
#pragma unroll
        for (int s = 0; s < 2; ++s)
#pragma unroll
            for (int fr = 0; fr < 4; ++fr)
#pragma unroll
                for (int nf = 0; nf < 2; ++nf)
                    acc[mh * 4 + fr][nh * 2 + nf] =
                        __builtin_amdgcn_mfma_f32_16x16x32_bf16(
                            af[fr][s], bf[nf][s], acc[mh * 4 + fr][nh * 2 + nf],
                            0, 0, 0);
        __builtin_amdgcn_s_setprio(0);
    };

    // ---- prologue: tile0 fully staged; tile1 B0,A0 in flight ----
    STAGE(0, 0, 0); STAGE(0, 1, 0); STAGE(0, 0, 1); STAGE(0, 1, 1);
    STAGE(1, 1, 0); STAGE(1, 0, 0);
    asm volatile("s_waitcnt vmcnt(4)" ::: "memory");   // tile0 resident
    __builtin_amdgcn_s_barrier();

    for (int j = 0; j < NT; ++j) {
        const __bf16* cA = sA[j & 1];
        const __bf16* cB = sB[j & 1];
        // ---- segment 1: C00 + C01; stage (j+1, B1), (j+1, A1) ----
        READ_A(cA, wr * 128);
        READ_B(bLo, cB, wc * 64);
        if (j + 1 < NT) STAGE(j + 1, 1, 1);
        MF(bLo, 0, 0);
        READ_B(bHi, cB, wc * 64 + 32);
        if (j + 1 < NT) STAGE(j + 1, 0, 1);
        MF(bHi, 0, 1);
        // barrier: all B-row reads of buf[j&1] complete before B0 overwrite
        __builtin_amdgcn_s_barrier();
        // ---- segment 2: C10; stage (j+2, B0) -> writes sB[j&1] rows 0..127 ----
        READ_A(cA, wr * 128 + 64);
        if (j + 2 < NT) STAGE(j + 2, 1, 0);
        MF(bLo, 1, 0);
        // barrier: A-hi reads of buf[j&1] complete before A0 overwrite
        __builtin_amdgcn_s_barrier();
        // ---- segment 3: C11; stage (j+2, A0); counted-vmcnt boundary ----
        if (j + 2 < NT) STAGE(j + 2, 0, 0);
        MF(bHi, 1, 1);
        if (j < NT - 2)       asm volatile("s_waitcnt vmcnt(4)" ::: "memory");
        else if (j == NT - 2) asm volatile("s_waitcnt vmcnt(0)" ::: "memory");
        __builtin_amdgcn_s_barrier();   // tile j+1 resident for all waves
    }

    // ---- epilogue: bias + bf16 store ----
#pragma unroll
    for (int mi = 0; mi < 8; ++mi) {
#pragma unroll
        for (int p = 0; p < 4; ++p) {
            const int m = m0 + wr * 128 + mi * 16 + quad * 4 + p;
#pragma unroll
            for (int ni = 0; ni < 4; ++ni) {
                const int n = n0 + wc * 64 + ni * 16 + lrow;
                C[(long)m * ldc + n] = (__bf16)(acc[mi][ni][p] + bias[n]);
            }
        }
    }
}

// ---------------------------------------------------------------------------
// bf16 MFMA GEMM (m97 structure): C = act(A @ Bt^T + bias)  [kept for heads]
// ---------------------------------------------------------------------------
#define TK 32
template <int ACT, int OUT_BF16, int SWZ>  // ACT: 1 = exact GELU
__global__ __launch_bounds__(256) void mfma_gemm(
    const __bf16* __restrict__ Abase, const __bf16* __restrict__ Btbase,
    const float* __restrict__ biasBase, float* __restrict__ Cf,
    __bf16* __restrict__ Cb,
    int M, int N, int K, int lda, int ldb, int ldc,
    long sA, long sB, long sBias, long sC)
{
    const int z = blockIdx.z;
    const __bf16* A  = Abase  + (long)z * sA;
    const __bf16* Bt = Btbase + (long)z * sB;
    const float* bias = biasBase + (long)z * sBias;

    int bx = blockIdx.x, by = blockIdx.y;
    if (SWZ) {  // grid must be 24 x 128
        int lid = by * 24 + bx;
        int xcd = lid & 7, s = lid >> 3;       // s: 0..383
        by = (xcd >> 1) * 32 + s / 12;
        bx = (xcd & 1) * 12 + s % 12;
    }
    const int m0 = by * 128;
    const int n0 = bx * 128;

    __shared__ __bf16 sAt[128 * TK];   // [m][k]
    __shared__ __bf16 sBt[128 * TK];   // [n][k]

    const int t    = threadIdx.x;
    const int wv   = t >> 6;
    const int lane = t & 63;
    const int quad = lane >> 4;
    const int lrow = lane & 15;
    const int wm = (wv >> 1) * 64;
    const int wn = (wv & 1) * 64;

    f32x4 acc[4][4] = {};

    const int sr = t >> 2;
    const int sk = (t & 3) * 8;
    __bf16* la0 = sAt + wv * 512;
    __bf16* la1 = sAt + 64 * TK + wv * 512;
    __bf16* lb0 = sBt + wv * 512;
    __bf16* lb1 = sBt + 64 * TK + wv * 512;

    for (int k0 = 0; k0 < K; k0 += TK) {
        gld_lds16(A  + (long)(m0 + sr)      * lda + k0 + sk, la0);
        gld_lds16(A  + (long)(m0 + 64 + sr) * lda + k0 + sk, la1);
        gld_lds16(Bt + (long)(n0 + sr)      * ldb + k0 + sk, lb0);
        gld_lds16(Bt + (long)(n0 + 64 + sr) * ldb + k0 + sk, lb1);
        __syncthreads();

        bf16x8 af[4], bfr[4];
#pragma unroll
        for (int i = 0; i < 4; ++i)
            af[i] = *(const bf16x8*)(sAt + (wm + i * 16 + lrow) * TK + quad * 8);
#pragma unroll
        for (int j = 0; j < 4; ++j)
            bfr[j] = *(const bf16x8*)(sBt + (wn + j * 16 + lrow) * TK + quad * 8);
#pragma unroll
        for (int i = 0; i < 4; ++i)
#pragma unroll
            for (int j = 0; j < 4; ++j)
                acc[i][j] = __builtin_amdgcn_mfma_f32_16x16x32_bf16(
                    af[i], bfr[j], acc[i][j], 0, 0, 0);
        __syncthreads();
    }

#pragma unroll
    for (int i = 0; i < 4; ++i) {
#pragma unroll
        for (int p = 0; p < 4; ++p) {
            const int m = m0 + wm + i * 16 + quad * 4 + p;
#pragma unroll
            for (int j = 0; j < 4; ++j) {
                const int n = n0 + wn + j * 16 + lrow;
                float val = acc[i][j][p] + bias[n];
                if (ACT == 1) val = 0.5f * val * (1.0f + erff(val * 0.70710678118654752f));
                if (OUT_BF16) Cb[(long)z * sC + (long)m * ldc + n] = (__bf16)val;
                else          Cf[(long)z * sC + (long)m * ldc + n] = val;
            }
        }
    }
}

// ---------------------------------------------------------------------------
// fp32 -> bf16 flat cast
// ---------------------------------------------------------------------------
__global__ __launch_bounds__(256) void cast_kernel(
    const float* __restrict__ in, __bf16* __restrict__ out)
{
    long i = ((long)blockIdx.x * 256 + threadIdx.x) * 4;
    float4 v = *(const float4*)(in + i);
    bf16x4 o = {(__bf16)v.x, (__bf16)v.y, (__bf16)v.z, (__bf16)v.w};
    *(bf16x4*)(out + i) = o;
}

// ---------------------------------------------------------------------------
// Generic transpose + cast: fp32 [R][C] -> bf16 [C][R], batched over z.
// ---------------------------------------------------------------------------
__global__ __launch_bounds__(256) void transpose_cast_kernel(
    const float* __restrict__ in, __bf16* __restrict__ out,
    int R, int C, long sIn, long sOut)
{
    const float* src = in + (long)blockIdx.z * sIn;
    __bf16* dst = out + (long)blockIdx.z * sOut;
    __shared__ float tile[32][33];
    const int r0 = blockIdx.y * 32, c0 = blockIdx.x * 32;
    const int tx = threadIdx.x & 31, ty = threadIdx.x >> 5;
#pragma unroll
    for (int i = 0; i < 32; i += 8)
        tile[ty + i][tx] = src[(long)(r0 + ty + i) * C + c0 + tx];
    __syncthreads();
#pragma unroll
    for (int i = 0; i < 32; i += 8)
        dst[(long)(c0 + ty + i) * R + r0 + tx] = (__bf16)tile[tx][ty + i];
}

// ---------------------------------------------------------------------------
// Merged Wq/Wk/Wv transpose: z in [0,9) -> layer z/3, tensor z%3.
// ---------------------------------------------------------------------------
__global__ __launch_bounds__(256) void transpose_qkv_kernel(
    const float* __restrict__ Wq, const float* __restrict__ Wk,
    const float* __restrict__ Wv, __bf16* __restrict__ out)
{
    const int zz = blockIdx.z;
    const int layer = zz / 3, which = zz - layer * 3;
    const float* src = (which == 0 ? Wq : which == 1 ? Wk : Wv) + (long)layer * 1048576;
    __bf16* dst = out + (long)layer * 3145728 + (long)which * 1048576;
    __shared__ float tile[32][33];
    const int r0 = blockIdx.y * 32, c0 = blockIdx.x * 32;
    const int tx = threadIdx.x & 31, ty = threadIdx.x >> 5;
#pragma unroll
    for (int i = 0; i < 32; i += 8)
        tile[ty + i][tx] = src[(long)(r0 + ty + i) * 1024 + c0 + tx];
    __syncthreads();
#pragma unroll
    for (int i = 0; i < 32; i += 8)
        dst[(long)(c0 + ty + i) * 1024 + r0 + tx] = (__bf16)tile[tx][ty + i];
}

// ---------------------------------------------------------------------------
// Concatenate bq|bk|bv per layer into [L][3072]
// ---------------------------------------------------------------------------
__global__ __launch_bounds__(256) void qkv_bias_kernel(
    const float* __restrict__ bq, const float* __restrict__ bk,
    const float* __restrict__ bv, float* __restrict__ ob)
{
    int i = blockIdx.x * 256 + threadIdx.x;
    if (i >= LL * 3072) return;
    int l = i / 3072, j = i - l * 3072;
    float v = (j < 1024) ? bq[l * 1024 + j]
            : (j < 2048) ? bk[l * 1024 + j - 1024]
                         : bv[l * 1024 + j - 2048];
    ob[i] = v;
}

// ---------------------------------------------------------------------------
// Wave-per-row LayerNorm over H=1024: 4 rows per block, shuffle reductions.
// ---------------------------------------------------------------------------
__global__ __launch_bounds__(256) void ln_kernel(
    const __bf16* __restrict__ x, const float* __restrict__ g,
    const float* __restrict__ b, __bf16* __restrict__ outb)
{
    const int wv = threadIdx.x >> 6, lane = threadIdx.x & 63;
    const long row = blockIdx.x * 4 + wv;
    const __bf16* xr = x + row * HH_;
    float v[16];
    float s = 0.f, s2 = 0.f;
#pragma unroll
    for (int i = 0; i < 4; ++i) {
        bf16x4 vb = *(const bf16x4*)(xr + i * 256 + lane * 4);
#pragma unroll
        for (int j = 0; j < 4; ++j) {
            float f = (float)vb[j];
            v[i * 4 + j] = f; s += f; s2 += f * f;
        }
    }
#pragma unroll
    for (int m = 1; m < 64; m <<= 1) { s += __shfl_xor(s, m); s2 += __shfl_xor(s2, m); }
    float mu = s * (1.0f / 1024.0f);
    float var = s2 * (1.0f / 1024.0f) - mu * mu;
    float rstd = rsqrtf(var + 1e-5f);
    __bf16* orow = outb + row * HH_;
#pragma unroll
    for (int i = 0; i < 4; ++i) {
        float4 gv = *(const float4*)(g + i * 256 + lane * 4);
        float4 bv = *(const float4*)(b + i * 256 + lane * 4);
        bf16x4 ob = {(__bf16)((v[i*4+0] - mu) * rstd * gv.x + bv.x),
                     (__bf16)((v[i*4+1] - mu) * rstd * gv.y + bv.y),
                     (__bf16)((v[i*4+2] - mu) * rstd * gv.z + bv.z),
                     (__bf16)((v[i*4+3] - mu) * rstd * gv.w + bv.w)};
        *(bf16x4*)(orow + i * 256 + lane * 4) = ob;
    }
}

// ---------------------------------------------------------------------------
// Fused attention per batch z: scores (MFMA) -> sinkhorn -> P@V.
// R5: sinkhorn row/col phases use 4-lane-group shfl reductions (thread t
// owns row t>>2, cols (t&3)*16..+15) -> no ps[][] LDS round-trip and only
// 2 barriers per iteration (was 4).
// ---------------------------------------------------------------------------
__global__ __launch_bounds__(256) void attn_kernel(
    const __bf16* __restrict__ qkv, __bf16* __restrict__ att)
{
    const int z = blockIdx.x;
    __shared__ __bf16 sQ[64 * 32];
    __shared__ __bf16 sK[64 * 32];
    __shared__ float la[64 * 65];
    __shared__ __bf16 sP[64 * 68];    // exp(P) bf16, padded
    __shared__ __bf16 sVT[64 * 68];   // V^T tile [n][c], padded

    const int t = threadIdx.x;
    const int wv = t >> 6, lane = t & 63;
    const int quad = lane >> 4, lrow = lane & 15;
    const int wm = (wv >> 1) * 32, wn = (wv & 1) * 32;

    // ---- phase 1: scores = Q K^T / 32 -> la ----
    {
        const int srow = t >> 2;
        const int skoff = (t & 3) * 8;
        __bf16* lq = sQ + wv * 512;
        __bf16* lk = sK + wv * 512;
        const __bf16* Q = qkv + (long)z * 64 * 3072;
        const __bf16* K = Q + 1024;

        f32x4 acc[2][2] = {};
        for (int k0 = 0; k0 < 1024; k0 += 32) {
            gld_lds16(Q + (long)srow * 3072 + k0 + skoff, lq);
            gld_lds16(K + (long)srow * 3072 + k0 + skoff, lk);
            __syncthreads();
            bf16x8 af[2], bfr[2];
#pragma unroll
            for (int i = 0; i < 2; ++i)
                af[i] = *(const bf16x8*)(sQ + (wm + i * 16 + lrow) * 32 + quad * 8);
#pragma unroll
            for (int j = 0; j < 2; ++j)
                bfr[j] = *(const bf16x8*)(sK + (wn + j * 16 + lrow) * 32 + quad * 8);
#pragma unroll
            for (int i = 0; i < 2; ++i)
#pragma unroll
                for (int j = 0; j < 2; ++j)
                    acc[i][j] = __builtin_amdgcn_mfma_f32_16x16x32_bf16(
                        af[i], bfr[j], acc[i][j], 0, 0, 0);
            __syncthreads();
        }
#pragma unroll
        for (int i = 0; i < 2; ++i)
#pragma unroll
            for (int p = 0; p < 4; ++p) {
                const int r = wm + i * 16 + quad * 4 + p;
#pragma unroll
                for (int j = 0; j < 2; ++j)
                    la[r * 65 + wn + j * 16 + lrow] = acc[i][j][p] * 0.03125f;
            }
        __syncthreads();
    }

    // ---- phase 2: sinkhorn, 50 iters, no max subtraction ----
    // |initial scores| <= ~2, so exp is safe; after the first row
    // normalization all entries are <= 0.
    {
        const int rr = t >> 2;              // owned row (row phase) / col (col)
        const int cc0 = (t & 3) * 16;       // owned 16-chunk
        for (int it = 0; it < 50; ++it) {
            {   // row phase: thread owns (row rr, cols cc0..cc0+15)
                float vr[16];
                float sum = 0.f;
#pragma unroll
                for (int i = 0; i < 16; ++i) vr[i] = la[rr * 65 + cc0 + i];
#pragma unroll
                for (int i = 0; i < 16; ++i) sum += __expf(vr[i]);
                sum += __shfl_xor(sum, 1);
                sum += __shfl_xor(sum, 2);
                float lse = __logf(sum);
#pragma unroll
                for (int i = 0; i < 16; ++i) la[rr * 65 + cc0 + i] = vr[i] - lse;
                __syncthreads();
            }
            {   // col phase: thread owns (col rr, rows cc0..cc0+15)
                float vr[16];
                float sum = 0.f;
#pragma unroll
                for (int i = 0; i < 16; ++i) vr[i] = la[(cc0 + i) * 65 + rr];
#pragma unroll
                for (int i = 0; i < 16; ++i) sum += __expf(vr[i]);
                sum += __shfl_xor(sum, 1);
                sum += __shfl_xor(sum, 2);
                float lse = __logf(sum);
#pragma unroll
                for (int i = 0; i < 16; ++i) la[(cc0 + i) * 65 + rr] = vr[i] - lse;
                __syncthreads();
            }
        }
    }

    // ---- phase 3: P = exp(la) -> bf16 sP ----
#pragma unroll
    for (int i = 0; i < 16; ++i) {
        int idx = t + i * 256;
        int r = idx >> 6, c = idx & 63;
        sP[r * 68 + c] = (__bf16)__expf(la[r * 65 + c]);
    }
    __syncthreads();

    // ---- phase 4: att = P @ V via MFMA, 16 column tiles of 64 ----
    const __bf16* V = qkv + (long)z * 64 * 3072 + 2048;
    const int vc = t >> 2;            // V row (agent c), 0..63
    const int vn = (t & 3) * 16;      // n offset within tile
    for (int tile = 0; tile < 16; ++tile) {
        bf16x8 v0 = *(const bf16x8*)(V + (long)vc * 3072 + tile * 64 + vn);
        bf16x8 v1 = *(const bf16x8*)(V + (long)vc * 3072 + tile * 64 + vn + 8);
#pragma unroll
        for (int j = 0; j < 8; ++j) sVT[(vn + j) * 68 + vc] = v0[j];
#pragma unroll
        for (int j = 0; j < 8; ++j) sVT[(vn + 8 + j) * 68 + vc] = v1[j];
        __syncthreads();

        f32x4 pacc[2][2] = {};
#pragma unroll
        for (int kb = 0; kb < 2; ++kb) {
            bf16x8 af[2], bfr[2];
#pragma unroll
            for (int i = 0; i < 2; ++i) {
                const __bf16* p = sP + (wm + i * 16 + lrow) * 68 + kb * 32 + quad * 8;
                bf16x4 lo = *(const bf16x4*)p;
                bf16x4 hi = *(const bf16x4*)(p + 4);
                af[i] = bf16x8{lo[0], lo[1], lo[2], lo[3], hi[0], hi[1], hi[2], hi[3]};
            }
#pragma unroll
            for (int j = 0; j < 2; ++j) {
                const __bf16* p = sVT + (wn + j * 16 + lrow) * 68 + kb * 32 + quad * 8;
                bf16x4 lo = *(const bf16x4*)p;
                bf16x4 hi = *(const bf16x4*)(p + 4);
                bfr[j] = bf16x8{lo[0], lo[1], lo[2], lo[3], hi[0], hi[1], hi[2], hi[3]};
            }
#pragma unroll
            for (int i = 0; i < 2; ++i)
#pragma unroll
                for (int j = 0; j < 2; ++j)
                    pacc[i][j] = __builtin_amdgcn_mfma_f32_16x16x32_bf16(
                        af[i], bfr[j], pacc[i][j], 0, 0, 0);
        }
#pragma unroll
        for (int i = 0; i < 2; ++i)
#pragma unroll
            for (int p = 0; p < 4; ++p) {
                const int r = wm + i * 16 + quad * 4 + p;
#pragma unroll
                for (int j = 0; j < 2; ++j) {
                    const int n = tile * 64 + wn + j * 16 + lrow;
                    att[((long)z * 64 + r) * HH_ + n] = (__bf16)pacc[i][j][p];
                }
            }
        __syncthreads();
    }
}

// ---------------------------------------------------------------------------
// Wave-per-row mix: 4 rows per block, shuffle reductions, no barriers.
// ---------------------------------------------------------------------------
__global__ __launch_bounds__(256) void mix_kernel(
    const __bf16* __restrict__ nsb_in, const __bf16* __restrict__ att,
    const float* __restrict__ ab, const float* __restrict__ sf,
    __bf16* __restrict__ h,
    const float* __restrict__ ig, const float* __restrict__ ib,
    const float* __restrict__ g2, const float* __restrict__ b2p, int doLN,
    __bf16* __restrict__ nsb_out)
{
    const int wv = threadIdx.x >> 6, lane = threadIdx.x & 63;
    const long row = blockIdx.x * 4 + wv;
    const int a = (int)(row & 63);
    const float sfa = sf[a];

    const __bf16* nr = nsb_in + row * HH_;
    const __bf16* ar = att + row * HH_;
    const float* abr = ab + (long)a * HH_;

    float sc[16];
    float nrm2 = 0.f;
#pragma unroll
    for (int i = 0; i < 4; ++i) {
        bf16x4 nv = *(const bf16x4*)(nr + i * 256 + lane * 4);
        bf16x4 av = *(const bf16x4*)(ar + i * 256 + lane * 4);
        float4 a4 = *(const float4*)(abr + i * 256 + lane * 4);
        float v0 = (0.1f * (float)nv[0] + 0.9f * (float)av[0] + a4.x) * sfa;
        float v1 = (0.1f * (float)nv[1] + 0.9f * (float)av[1] + a4.y) * sfa;
        float v2 = (0.1f * (float)nv[2] + 0.9f * (float)av[2] + a4.z) * sfa;
        float v3 = (0.1f * (float)nv[3] + 0.9f * (float)av[3] + a4.w) * sfa;
        sc[i*4+0] = v0; sc[i*4+1] = v1; sc[i*4+2] = v2; sc[i*4+3] = v3;
        nrm2 += v0 * v0 + v1 * v1 + v2 * v2 + v3 * v3;
    }
#pragma unroll
    for (int m = 1; m < 64; m <<= 1) nrm2 += __shfl_xor(nrm2, m);
    float norm = sqrtf(nrm2);
    float inv = norm > 1.0f ? 1.0f / norm : 1.0f;

    __bf16* hr = h + row * HH_;
    float hn[16];
    float s = 0.f, s2 = 0.f;
#pragma unroll
    for (int i = 0; i < 4; ++i) {
        bf16x4 hv = *(const bf16x4*)(hr + i * 256 + lane * 4);
#pragma unroll
        for (int j = 0; j < 4; ++j) {
            float f = (float)hv[j] + sc[i * 4 + j] * inv;
            hn[i * 4 + j] = f; s += f; s2 += f * f;
        }
    }
    if (!doLN) {
#pragma unroll
        for (int i = 0; i < 4; ++i) {
            bf16x4 ob = {(__bf16)hn[i*4+0], (__bf16)hn[i*4+1],
                         (__bf16)hn[i*4+2], (__bf16)hn[i*4+3]};
            *(bf16x4*)(hr + i * 256 + lane * 4) = ob;
        }
        return;
    }
#pragma unroll
    for (int m = 1; m < 64; m <<= 1) { s += __shfl_xor(s, m); s2 += __shfl_xor(s2, m); }
    float mu = s * (1.0f / 1024.0f);
    float var = s2 * (1.0f / 1024.0f) - mu * mu;
    float rstd = rsqrtf(var + 1e-5f);
    float s_1 = 0.f, s2_1 = 0.f;
#pragma unroll
    for (int i = 0; i < 4; ++i) {
        float4 gv = *(const float4*)(ig + i * 256 + lane * 4);
        float4 bv = *(const float4*)(ib + i * 256 + lane * 4);
        float f0 = (hn[i*4+0] - mu) * rstd * gv.x + bv.x;
        float f1 = (hn[i*4+1] - mu) * rstd * gv.y + bv.y;
        float f2 = (hn[i*4+2] - mu) * rstd * gv.z + bv.z;
        float f3 = (hn[i*4+3] - mu) * rstd * gv.w + bv.w;
        hn[i*4+0] = f0; hn[i*4+1] = f1; hn[i*4+2] = f2; hn[i*4+3] = f3;
        s_1 += f0 + f1 + f2 + f3;
        s2_1 += f0 * f0 + f1 * f1 + f2 * f2 + f3 * f3;
        bf16x4 ob = {(__bf16)f0, (__bf16)f1, (__bf16)f2, (__bf16)f3};
        *(bf16x4*)(hr + i * 256 + lane * 4) = ob;
    }
#pragma unroll
    for (int m = 1; m < 64; m <<= 1) { s_1 += __shfl_xor(s_1, m); s2_1 += __shfl_xor(s2_1, m); }
    mu = s_1 * (1.0f / 1024.0f);
    var = s2_1 * (1.0f / 1024.0f) - mu * mu;
    rstd = rsqrtf(var + 1e-5f);
    __bf16* nor = nsb_out + row * HH_;
#pragma unroll
    for (int i = 0; i < 4; ++i) {
        float4 gv = *(const float4*)(g2 + i * 256 + lane * 4);
        float4 bv = *(const float4*)(b2p + i * 256 + lane * 4);
        bf16x4 ob = {(__bf16)((hn[i*4+0] - mu) * rstd * gv.x + bv.x),
                     (__bf16)((hn[i*4+1] - mu) * rstd * gv.y + bv.y),
                     (__bf16)((hn[i*4+2] - mu) * rstd * gv.z + bv.z),
                     (__bf16)((hn[i*4+3] - mu) * rstd * gv.w + bv.w)};
        *(bf16x4*)(nor + i * 256 + lane * 4) = ob;
    }
}

// ---------------------------------------------------------------------------
extern "C" void kernel_launch(void* const* d_in, const int* in_sizes, int n_in,
                              void* d_out, int out_size, void* d_ws, size_t ws_size,
                              hipStream_t stream)
{
    const float* agent_states = (const float*)d_in[0];
    const float* Win   = (const float*)d_in[1];
    const float* bin_  = (const float*)d_in[2];
    const float* ln_g  = (const float*)d_in[3];
    const float* ln_b  = (const float*)d_in[4];
    const float* Wq    = (const float*)d_in[5];
    const float* bq    = (const float*)d_in[6];
    const float* Wk    = (const float*)d_in[7];
    const float* bk    = (const float*)d_in[8];
    const float* Wv    = (const float*)d_in[9];
    const float* bv    = (const float*)d_in[10];
    const float* ab    = (const float*)d_in[11];
    const float* sf    = (const float*)d_in[12];
    const float* ilg   = (const float*)d_in[13];
    const float* ilb   = (const float*)d_in[14];
    const float* W1    = (const float*)d_in[15];
    const float* b1    = (const float*)d_in[16];
    const float* W2    = (const float*)d_in[17];
    const float* b2    = (const float*)d_in[18];
    float* out = (float*)d_out;

    // ---- workspace layout ----
    float* qbias = (float*)d_ws;                 // 16384 floats (9216 used)
    __bf16* base = (__bf16*)(qbias + 16384);
    __bf16* nsb   = base;                        // HN
    __bf16* h     = nsb + HN;                    // HN
    __bf16* att   = h + HN;                      // HN
    __bf16* qkvb  = att + HN;                    // 3*HN = 50,331,648
    __bf16* Wqkvt = qkvb + 3 * HN;               // 9,437,184
    // pre-loop overlays (att unused until layer 0 attention):
    __bf16* asb  = att;                          // 8,388,608
    __bf16* Wint = att + 8388608;                // 524,288
    // post-loop overlays (qkvb dead after last attention):
    __bf16* W1t = qkvb;                          // 33,554,432
    __bf16* W2t = qkvb + 33554432;               // 8,388,608
    __bf16* yb  = qkvb + 41943040;               // 8,388,608

    // ---- prep: casts / packs ----
    cast_kernel<<<8192, 256, 0, stream>>>(agent_states, asb);
    transpose_cast_kernel<<<dim3(32, 16, 1), 256, 0, stream>>>(Win, Wint, 512, 1024, 0, 0);
    transpose_qkv_kernel<<<dim3(32, 32, 9), 256, 0, stream>>>(Wq, Wk, Wv, Wqkvt);
    qkv_bias_kernel<<<36, 256, 0, stream>>>(bq, bk, bv, qbias);

    // ---- input projection: h(bf16) = asb @ Win^T + bin  (256x256) ----
    mfma_gemm256<<<dim3(4, 64), 512, 0, stream>>>(asb, Wint, bin_, h, DIN, HH_);
    ln_kernel<<<ROWS / 4, 256, 0, stream>>>(h, ln_g, ln_b, nsb);

    for (int i = 0; i < LL; ++i) {
        // QKV: [16384 x 3072] = nsb @ [Wq^T|Wk^T|Wv^T]  (256x256)
        mfma_gemm256<<<dim3(12, 64), 512, 0, stream>>>(
            nsb, Wqkvt + (long)i * 3145728, qbias + i * 3072, qkvb, HH_, 3072);
        attn_kernel<<<BB, 256, 0, stream>>>(qkvb, att);
        const int last = (i == LL - 1);
        mix_kernel<<<ROWS / 4, 256, 0, stream>>>(
            nsb, att, ab + (long)i * AA * HH_, sf + i * AA, h,
            ilg + (last ? 0 : i) * HH_, ilb + (last ? 0 : i) * HH_,
            ln_g + (last ? 0 : (i + 1)) * HH_, ln_b + (last ? 0 : (i + 1)) * HH_,
            last ? 0 : 1, nsb);
    }

    // ---- heads ----
    transpose_cast_kernel<<<dim3(16, 32, 64), 256, 0, stream>>>(W1, W1t, 1024, 512,
                                                                524288, 524288);
    transpose_cast_kernel<<<dim3(8, 16, 64), 256, 0, stream>>>(W2, W2t, 512, 256,
                                                               131072, 131072);
    mfma_gemm<1, 1, 0><<<dim3(4, 2, 64), 256, 0, stream>>>(
        h, W1t, b1, nullptr, yb, BB, HHALF, HH_,
        AA * HH_, HH_, AA * HHALF, HH_, (long)HHALF * HH_, HHALF, HHALF);
    mfma_gemm<0, 0, 0><<<dim3(2, 2, 64), 256, 0, stream>>>(
        yb, W2t, b2, out, nullptr, BB, OUTD, HHALF,
        AA * HHALF, HHALF, AA * OUTD, HHALF, (long)OUTD * HHALF, OUTD, OUTD);
}